// Round 14
// baseline (327.891 us; speedup 1.0000x reference)
//
#include <hip/hip_runtime.h>
#include <stdint.h>

typedef short short8 __attribute__((ext_vector_type(8)));
typedef float f32x16 __attribute__((ext_vector_type(16)));
typedef unsigned ux4 __attribute__((ext_vector_type(4)));

#define WIN  288
#define CAP  384
#define FBLK 1024

#define OFF_WF    0
#define OFF_MSG   49152
#define OFF_SC    (OFF_MSG + CAP*64*4)      /* 147456 */
#define OFF_RED   (OFF_SC + CAP*4)          /* 148992 */
#define OFF_CTL   (OFF_RED + 64)            /* 149056 */
#define OFF_PART  (OFF_CTL + 16)            /* 149072 */
#define OFF_ACC   (OFF_PART + 16*128*4)     /* 157264 */
#define LDS_TOT   (OFF_ACC + 512)           /* 157776 */

__device__ __forceinline__ unsigned cvtpk(float lo, float hi){
  unsigned r;
  asm("v_cvt_pk_bf16_f32 %0, %1, %2" : "=v"(r) : "v"(lo), "v"(hi));
  return r;
}

__device__ __forceinline__ short8 frag_from(unsigned a, unsigned b, unsigned c, unsigned d){
  union { unsigned u[4]; short8 s; } t;
  t.u[0] = a; t.u[1] = b; t.u[2] = c; t.u[3] = d;
  return t.s;
}

// ---------------- setup: W-frag pack + x->bf16 cast + target histogram ----------------
__global__ void k_setup(const float* __restrict__ x, uint2* __restrict__ xb, int n4,
                        const int* __restrict__ ei, int* __restrict__ rowptr, int E,
                        const float* __restrict__ W1, const float* __restrict__ W2,
                        ux4* __restrict__ Wf)
{
  const long long tid = (long long)blockIdx.x * 256 + threadIdx.x;
  if (tid < 48 * 64) {
    const int f = (int)(tid >> 6), l = (int)(tid & 63);
    const int r = l & 31, hh = l >> 5;
    float v[8];
    if (f < 16) {
      const int mf = f >> 2, ks = f & 3;
      const int c = 32 * mf + r, kb = ks * 16 + hh * 8;
#pragma unroll
      for (int j = 0; j < 8; ++j) v[j] = W1[(kb + j) * 128 + c];
    } else {
      const int f2 = f - 16, mf2 = f2 >> 3, ks = f2 & 7;
      const int o = 32 * mf2 + r, cb = ks * 16 + hh * 8;
#pragma unroll
      for (int j = 0; j < 8; ++j) v[j] = W2[(cb + j) * 128 + o];
    }
    ux4 d;
    d.x = cvtpk(v[0], v[1]); d.y = cvtpk(v[2], v[3]);
    d.z = cvtpk(v[4], v[5]); d.w = cvtpk(v[6], v[7]);
    Wf[(long long)f * 64 + l] = d;
  }
  const long long tot = (n4 > E) ? n4 : E;
  for (long long i = tid; i < tot; i += (long long)gridDim.x * 256) {
    if (i < n4) {
      float4 v = ((const float4*)x)[i];
      uint2 o; o.x = cvtpk(v.x, v.y); o.y = cvtpk(v.z, v.w);
      xb[i] = o;
    }
    if (i < E) atomicAdd(&rowptr[ei[E + i]], 1);
  }
}

// ---------------- scan: exclusive prefix + tile-first marking ----------------
__global__ __launch_bounds__(1024)
void k_scan(int* __restrict__ p, int N, int* __restrict__ tileFirst, int ntiles){
  __shared__ int ls[1024];
  const int t = threadIdx.x;
  const int chunk = (N + 1023) >> 10;
  const int c0 = t * chunk, c1 = min(N, c0 + chunk);
  int s = 0;
  for (int i = c0; i < c1; ++i) s += p[i];
  ls[t] = s;
  __syncthreads();
  for (int off = 1; off < 1024; off <<= 1) {
    int add = (t >= off) ? ls[t - off] : 0;
    __syncthreads();
    ls[t] += add;
    __syncthreads();
  }
  int run = (t == 0) ? 0 : ls[t - 1];
  for (int i = c0; i < c1; ++i) {
    int v = p[i];
    p[i] = run;
    int tw = run / WIN;
    if (tw > ntiles - 1) tw = ntiles - 1;
    atomicMin(&tileFirst[tw], i);
    run += v;
  }
}

__global__ void k_fill(const int* __restrict__ ei, int* __restrict__ rowptr,
                       int* __restrict__ eidx, int E){
  for (long long i = (long long)blockIdx.x * 256 + threadIdx.x; i < E;
       i += (long long)gridDim.x * 256) {
    int tg = ei[E + i];
    int pos = atomicAdd(&rowptr[tg], 1);
    eidx[pos] = (int)i;
  }
}

// ---------------- phase A: MLP for one chunk of <=CAP edges, messages -> LDS ----------
__device__ __forceinline__ void mlp_chunk(
    int e0, int cnt, int oversized,
    const unsigned* __restrict__ xb, const int* __restrict__ ei,
    const float* __restrict__ ea, const float* __restrict__ b1,
    const float* __restrict__ b2, const float* __restrict__ attn,
    const int* __restrict__ eidx, float* __restrict__ scoreS,
    const ux4* sWf, unsigned* sMsg, float* sScore,
    int lane, int wv, int h, int r31)
{
  if (wv * 32 >= cnt) return;
  const int li  = wv * 32 + r31;
  const int lic = (li < cnt) ? li : (cnt - 1);
  const long long p = (long long)e0 + lic;
  const int e   = eidx[p];
  const int src = ei[e];

  const float* er = ea + (long long)e * 64 + h * 8;
  float4 v[8];
#pragma unroll
  for (int ks = 0; ks < 4; ++ks) {
    v[2*ks]   = *(const float4*)(er + ks * 16);
    v[2*ks+1] = *(const float4*)(er + ks * 16 + 4);
  }
  float ss = 0.f;
#pragma unroll
  for (int k8 = 0; k8 < 8; ++k8) {
    ss = fmaf(v[k8].x, v[k8].x, ss); ss = fmaf(v[k8].y, v[k8].y, ss);
    ss = fmaf(v[k8].z, v[k8].z, ss); ss = fmaf(v[k8].w, v[k8].w, ss);
  }
  ss += __shfl_xor(ss, 32);
  const float rin = 1.0f / (sqrtf(ss) + 1e-8f);
  unsigned eb[4][4];
#pragma unroll
  for (int ks = 0; ks < 4; ++ks) {
    eb[ks][0] = cvtpk(v[2*ks].x,   v[2*ks].y);
    eb[ks][1] = cvtpk(v[2*ks].z,   v[2*ks].w);
    eb[ks][2] = cvtpk(v[2*ks+1].x, v[2*ks+1].y);
    eb[ks][3] = cvtpk(v[2*ks+1].z, v[2*ks+1].w);
  }

  // L1: h = tanh(a1*rin + b1)
  unsigned hb[8][4];
#pragma unroll
  for (int mf = 0; mf < 4; ++mf) {
    f32x16 a1;
#pragma unroll
    for (int i = 0; i < 16; ++i) a1[i] = 0.f;
#pragma unroll
    for (int ks = 0; ks < 4; ++ks) {
      ux4 w = sWf[(mf * 4 + ks) * 64 + lane];
      a1 = __builtin_amdgcn_mfma_f32_32x32x16_bf16(
          frag_from(w.x, w.y, w.z, w.w),
          frag_from(eb[ks][0], eb[ks][1], eb[ks][2], eb[ks][3]), a1, 0, 0, 0);
    }
    float hv[16];
#pragma unroll
    for (int rq = 0; rq < 4; ++rq) {
      float4 bc = *(const float4*)(b1 + 32*mf + 8*rq + 4*h);
#pragma unroll
      for (int i = 0; i < 4; ++i) {
        float pre = fmaf(a1[rq*4+i], rin, ((const float*)&bc)[i]);
        float e2  = __expf(2.0f * pre);
        hv[rq*4+i] = 1.0f - 2.0f / (e2 + 1.0f);
      }
    }
#pragma unroll
    for (int q = 0; q < 2; ++q) {
      unsigned A = cvtpk(hv[q*8+0], hv[q*8+1]);
      unsigned B = cvtpk(hv[q*8+2], hv[q*8+3]);
      unsigned C = cvtpk(hv[q*8+4], hv[q*8+5]);
      unsigned D = cvtpk(hv[q*8+6], hv[q*8+7]);
      unsigned Axr = (unsigned)__shfl_xor((int)A, 32);
      unsigned Bxr = (unsigned)__shfl_xor((int)B, 32);
      unsigned Cxr = (unsigned)__shfl_xor((int)C, 32);
      unsigned Dxr = (unsigned)__shfl_xor((int)D, 32);
      hb[2*mf+q][0] = h ? Cxr : A;
      hb[2*mf+q][1] = h ? Dxr : B;
      hb[2*mf+q][2] = h ? C   : Axr;
      hb[2*mf+q][3] = h ? D   : Bxr;
    }
  }

  // L2 + epilogue -> LDS (swizzled 16B slots)
  const unsigned* xrow = xb + (long long)src * 64;
  float score = 0.f;
#pragma unroll
  for (int mf2 = 0; mf2 < 4; ++mf2) {
    uint2 xw[4];
#pragma unroll
    for (int rq = 0; rq < 4; ++rq)
      xw[rq] = *(const uint2*)(xrow + (32*mf2 + 8*rq + 4*h) / 2);
    f32x16 a2;
#pragma unroll
    for (int i = 0; i < 16; ++i) a2[i] = 0.f;
#pragma unroll
    for (int ks = 0; ks < 8; ++ks) {
      ux4 w = sWf[(16 + mf2 * 8 + ks) * 64 + lane];
      a2 = __builtin_amdgcn_mfma_f32_32x32x16_bf16(
          frag_from(w.x, w.y, w.z, w.w),
          frag_from(hb[ks][0], hb[ks][1], hb[ks][2], hb[ks][3]), a2, 0, 0, 0);
    }
    unsigned pk[8];
#pragma unroll
    for (int rq = 0; rq < 4; ++rq) {
      const int o0 = 32*mf2 + 8*rq + 4*h;
      float4 b2c = *(const float4*)(b2 + o0);
      float4 atc = *(const float4*)(attn + o0);
      float x0 = __uint_as_float(xw[rq].x << 16);
      float x1 = __uint_as_float(xw[rq].x & 0xffff0000u);
      float x2 = __uint_as_float(xw[rq].y << 16);
      float x3 = __uint_as_float(xw[rq].y & 0xffff0000u);
      float m0 = (a2[rq*4+0] + b2c.x) * x0;
      float m1 = (a2[rq*4+1] + b2c.y) * x1;
      float m2 = (a2[rq*4+2] + b2c.z) * x2;
      float m3 = (a2[rq*4+3] + b2c.w) * x3;
      score = fmaf(m0, atc.x, score);
      score = fmaf(m1, atc.y, score);
      score = fmaf(m2, atc.z, score);
      score = fmaf(m3, atc.w, score);
      pk[2*rq]   = cvtpk(m0, m1);
      pk[2*rq+1] = cvtpk(m2, m3);
    }
    const int s0slot = 4*mf2 + 2*h;
    const int m15 = li & 15;
    ux4 q0, q1;
    q0.x = pk[0]; q0.y = pk[1]; q0.z = pk[2]; q0.w = pk[3];
    q1.x = pk[4]; q1.y = pk[5]; q1.z = pk[6]; q1.w = pk[7];
    *(ux4*)&sMsg[li*64 + ((s0slot     ^ m15) << 2)] = q0;
    *(ux4*)&sMsg[li*64 + (((s0slot+1) ^ m15) << 2)] = q1;
  }
  score += __shfl_xor(score, 32);
  if (h == 0) {
    sScore[li] = score;
    if (oversized && li < cnt) scoreS[p] = score;
  }
}

__device__ __forceinline__ unsigned msg_ld(const unsigned* sMsg, int row, int lane){
  return sMsg[row*64 + ((((lane>>2) ^ (row & 15)) << 2) | (lane & 3))];
}

// ---------------- fused MLP + gather ----------------
__global__ __launch_bounds__(FBLK)
void k_fused(const unsigned* __restrict__ xb, const int* __restrict__ ei,
             const float* __restrict__ ea, const ux4* __restrict__ Wf,
             const float* __restrict__ b1, const float* __restrict__ b2,
             const float* __restrict__ attn, const int* __restrict__ eidx,
             const int* __restrict__ rowptr, const int* __restrict__ tileFirst,
             float* __restrict__ scoreS, float* __restrict__ wreg,
             float* __restrict__ out, int N, int E, int ntiles)
{
  extern __shared__ char smem[];
  ux4*      sWf    = (ux4*)(smem + OFF_WF);
  unsigned* sMsg   = (unsigned*)(smem + OFF_MSG);
  float*    sScore = (float*)(smem + OFF_SC);
  float*    sRed   = (float*)(smem + OFF_RED);
  float*    sCtl   = (float*)(smem + OFF_CTL);   // [0]=m [1]=s [2]=r
  float*    sPart  = (float*)(smem + OFF_PART);
  float*    sAcc   = (float*)(smem + OFF_ACC);

  const int tid  = threadIdx.x;
  const int lane = tid & 63;
  const int wv   = tid >> 6;
  const int h    = lane >> 5;
  const int r31  = lane & 31;

  for (int i = tid; i < 48*64; i += FBLK) sWf[i] = Wf[i];
  __syncthreads();

  for (int t = blockIdx.x; t < ntiles; t += gridDim.x) {
    const int nF = tileFirst[t];
    if (nF >= N) continue;                       // INF marker / empty window
    int t2 = t + 1;
    while (t2 < ntiles && tileFirst[t2] >= N) ++t2;
    const int nL = (t2 < ntiles) ? tileFirst[t2] - 1 : N - 1;

    int n  = nF;
    int s0 = n ? rowptr[n-1] : 0;
    while (n <= nL) {
      const int en = rowptr[n];
      const int dn = en - s0;
      if (dn > CAP) {
        // ---------- oversized node: online-softmax chunks ----------
        if (tid < 128) sAcc[tid] = 0.f;
        if (tid == 0) { sCtl[0] = -3.4e38f; sCtl[1] = 0.f; }
        __syncthreads();
        for (int c0 = 0; c0 < dn; c0 += CAP) {
          const int cnt = min(CAP, dn - c0);
          mlp_chunk(s0 + c0, cnt, 1, xb, ei, ea, b1, b2, attn, eidx, scoreS,
                    sWf, sMsg, sScore, lane, wv, h, r31);
          __syncthreads();
          float vmax = (tid < cnt) ? sScore[tid] : -3.4e38f;
#pragma unroll
          for (int off = 32; off; off >>= 1) vmax = fmaxf(vmax, __shfl_xor(vmax, off));
          if (lane == 0) sRed[wv] = vmax;
          __syncthreads();
          if (tid == 0) {
            float cm = sRed[0];
            for (int w = 1; w < 16; ++w) cm = fmaxf(cm, sRed[w]);
            float mn = fmaxf(sCtl[0], cm);
            sCtl[2] = __expf(sCtl[0] - mn);
            sCtl[0] = mn;
          }
          __syncthreads();
          const float mn = sCtl[0], r = sCtl[2];
          float ev = (tid < cnt) ? __expf(sScore[tid] - mn) : 0.f;
#pragma unroll
          for (int off = 32; off; off >>= 1) ev += __shfl_xor(ev, off);
          if (lane == 0) sRed[wv] = ev;
          float2 pacc; pacc.x = 0.f; pacc.y = 0.f;
          if (wv * 32 < cnt) {
            float pl = (lane < 32 && wv*32 + lane < cnt)
                     ? __expf(sScore[wv*32 + lane] - mn) : 0.f;
            const int jn = min(32, cnt - wv*32);
            for (int j2 = 0; j2 < jn; ++j2) {
              float pj = __shfl(pl, j2);
              unsigned md = msg_ld(sMsg, wv*32 + j2, lane);
              pacc.x = fmaf(pj, __uint_as_float(md << 16),          pacc.x);
              pacc.y = fmaf(pj, __uint_as_float(md & 0xffff0000u), pacc.y);
            }
          }
          sPart[wv*128 + 2*lane]     = pacc.x;
          sPart[wv*128 + 2*lane + 1] = pacc.y;
          __syncthreads();
          if (tid == 0) {
            float ssum = 0.f;
            for (int w = 0; w < 16; ++w) ssum += sRed[w];
            sCtl[1] = sCtl[1] * sCtl[2] + ssum;
          }
          if (tid < 128) {
            float tp = 0.f;
            for (int w = 0; w < 16; ++w) tp += sPart[w*128 + tid];
            sAcc[tid] = sAcc[tid] * r + tp;
          }
          __syncthreads();
        }
        const float mfin = sCtl[0];
        const float sfin = sCtl[1] + 1e-16f;
        for (int j = tid; j < dn; j += FBLK)
          wreg[eidx[s0 + j]] = __expf(scoreS[s0 + j] - mfin) / sfin;
        if (tid < 64) {
          const int mf2 = tid >> 4, hh = (tid >> 3) & 1, rq = (tid >> 1) & 3, hf = tid & 1;
          const int ch0 = 32*mf2 + 8*rq + 4*hh + 2*hf;
          float2 o; o.x = sAcc[2*tid]; o.y = sAcc[2*tid + 1];
          *(float2*)(out + (long long)n * 128 + ch0) = o;
        }
        __syncthreads();
        s0 = en; ++n;
        continue;
      }
      // ---------- batch of whole nodes, span <= CAP ----------
      int m = n, send = en;
      while (m < nL) {
        int nx = rowptr[m + 1];
        if (nx - s0 > CAP) break;
        send = nx; ++m;
      }
      mlp_chunk(s0, send - s0, 0, xb, ei, ea, b1, b2, attn, eidx, scoreS,
                sWf, sMsg, sScore, lane, wv, h, r31);
      __syncthreads();
      for (int nn = n + wv; nn <= m; nn += 16) {
        const int gs = nn ? rowptr[nn - 1] : 0;
        const int L  = rowptr[nn] - gs;
        const int ls = gs - s0;
        float2 acc; acc.x = 0.f; acc.y = 0.f;
        if (L <= 64) {
          float sc = (lane < L) ? sScore[ls + lane] : -3.4e38f;
          float mn = sc;
#pragma unroll
          for (int off = 32; off; off >>= 1) mn = fmaxf(mn, __shfl_xor(mn, off));
          float ex = (lane < L) ? __expf(sc - mn) : 0.f;
          float s = ex;
#pragma unroll
          for (int off = 32; off; off >>= 1) s += __shfl_xor(s, off);
          const float w = ex / (s + 1e-16f);
          if (lane < L) wreg[eidx[gs + lane]] = w;
          for (int j2 = 0; j2 < L; ++j2) {
            float wj = __shfl(w, j2);
            unsigned md = msg_ld(sMsg, ls + j2, lane);
            acc.x = fmaf(wj, __uint_as_float(md << 16),          acc.x);
            acc.y = fmaf(wj, __uint_as_float(md & 0xffff0000u), acc.y);
          }
        } else {
          float mr = -3.4e38f, s = 0.f;
          for (int c0 = 0; c0 < L; c0 += 64) {
            const int j = c0 + lane;
            float sc = (j < L) ? sScore[ls + j] : -3.4e38f;
            float cm = sc;
#pragma unroll
            for (int off = 32; off; off >>= 1) cm = fmaxf(cm, __shfl_xor(cm, off));
            const float mn = fmaxf(mr, cm);
            float ex = (j < L) ? __expf(sc - mn) : 0.f;
#pragma unroll
            for (int off = 32; off; off >>= 1) ex += __shfl_xor(ex, off);
            s = s * __expf(mr - mn) + ex;
            mr = mn;
          }
          const float inv = 1.0f / (s + 1e-16f);
          for (int c0 = 0; c0 < L; c0 += 64) {
            const int j = c0 + lane;
            float w = (j < L) ? __expf(sScore[ls + j] - mr) * inv : 0.f;
            if (j < L) wreg[eidx[gs + j]] = w;
            const int jn = min(64, L - c0);
            for (int j2 = 0; j2 < jn; ++j2) {
              float wj = __shfl(w, j2);
              unsigned md = msg_ld(sMsg, ls + c0 + j2, lane);
              acc.x = fmaf(wj, __uint_as_float(md << 16),          acc.x);
              acc.y = fmaf(wj, __uint_as_float(md & 0xffff0000u), acc.y);
            }
          }
        }
        const int mf2 = lane >> 4, hh = (lane >> 3) & 1, rq = (lane >> 1) & 3, hf = lane & 1;
        const int ch0 = 32*mf2 + 8*rq + 4*hh + 2*hf;
        *(float2*)(out + (long long)nn * 128 + ch0) = acc;
      }
      __syncthreads();
      s0 = send; n = m + 1;
    }
  }
}

extern "C" void kernel_launch(void* const* d_in, const int* in_sizes, int n_in,
                              void* d_out, int out_size, void* d_ws, size_t ws_size,
                              hipStream_t stream)
{
  const float* x    = (const float*)d_in[0];
  const int*   ei   = (const int*)d_in[1];
  const float* ea   = (const float*)d_in[2];
  const float* W1   = (const float*)d_in[3];
  const float* b1   = (const float*)d_in[4];
  const float* W2   = (const float*)d_in[5];
  const float* b2   = (const float*)d_in[6];
  const float* attn = (const float*)d_in[7];
  const int N = in_sizes[0] / 128;
  const int E = in_sizes[2] / 64;
  if (E <= 0 || N <= 0) return;
  const int ntiles = (E + WIN - 1) / WIN;

  float* out  = (float*)d_out;
  float* wreg = out + (long long)N * 128;

  auto al = [](size_t v){ return (v + 255) & ~(size_t)255; };
  char* wsb = (char*)d_ws;
  size_t oRow  = 0;                                  // N*4
  size_t oTile = al(oRow + (size_t)N * 4);           // ntiles*4
  size_t oEidx = al(oTile + (size_t)ntiles * 4);     // E*4
  size_t oScr  = al(oEidx + (size_t)E * 4);          // E*4
  size_t oXb   = al(oScr + (size_t)E * 4);           // N*256
  size_t oWf   = al(oXb + (size_t)N * 256);          // 48K
  size_t need  = oWf + 49152;
  if (ws_size < need) return;
  if ((size_t)out_size < (size_t)N * 128 + (size_t)E) return;

  int*      rowptr    = (int*)(wsb + oRow);
  int*      tileFirst = (int*)(wsb + oTile);
  int*      eidx      = (int*)(wsb + oEidx);
  float*    scoreS    = (float*)(wsb + oScr);
  unsigned* xb        = (unsigned*)(wsb + oXb);
  ux4*      Wf        = (ux4*)(wsb + oWf);

  (void)hipMemsetAsync(rowptr, 0, (size_t)N * 4, stream);
  (void)hipMemsetAsync(tileFirst, 0x7F, (size_t)ntiles * 4, stream);
  k_setup<<<1024, 256, 0, stream>>>(x, (uint2*)xb, N * 32, ei, rowptr, E, W1, W2, Wf);
  k_scan<<<1, 1024, 0, stream>>>(rowptr, N, tileFirst, ntiles);
  k_fill<<<1024, 256, 0, stream>>>(ei, rowptr, eidx, E);
  (void)hipFuncSetAttribute(reinterpret_cast<const void*>(&k_fused),
                            hipFuncAttributeMaxDynamicSharedMemorySize, LDS_TOT);
  const int grid = min(256, ntiles);
  k_fused<<<grid, FBLK, LDS_TOT, stream>>>(xb, ei, ea, Wf, b1, b2, attn,
                                           eidx, rowptr, tileFirst,
                                           scoreS, wreg, out, N, E, ntiles);
}